// Round 9
// baseline (203.765 us; speedup 1.0000x reference)
//
#include <hip/hip_runtime.h>

#define DEV static __device__ __forceinline__

typedef float f32x4 __attribute__((ext_vector_type(4)));
typedef int i32x4 __attribute__((ext_vector_type(4)));
typedef __bf16 bf16x8 __attribute__((ext_vector_type(8)));
typedef unsigned short u16x8 __attribute__((ext_vector_type(8)));
typedef unsigned short u16x4 __attribute__((ext_vector_type(4)));

#define MFMA(a, b, c) __builtin_amdgcn_mfma_f32_16x16x32_bf16((a), (b), (c), 0, 0, 0)

// B=8, T=2048, C=1024, H=64
#define TT 2048
#define CE 1024
#define HS 64

// ws layout (ushort elements unless noted)
#define WBT_E 0                   // [3][64 n][1024 k] bf16 (Wq scaled by log2e/32)
#define Q_E   196608              // [B*T][64] bf16
#define K_E   (Q_E + 1048576)
#define VT_E  (K_E + 1048576)     // [B][64 h][2048 t] bf16
#define PO_E  (VT_E + 1048576)    // [512 slots][64 row][64 h] bf16 partial O
#define PML_E (PO_E + 2097152)    // float [512][64 row][2] {m,l}

DEV unsigned short cvt_bf16(float f) {
    unsigned int u = __builtin_bit_cast(unsigned int, f);
    u += 0x7FFFu + ((u >> 16) & 1u);   // RNE (finite inputs)
    return (unsigned short)(u >> 16);
}

DEV float bf2f(unsigned short v) {
    unsigned int u = ((unsigned int)v) << 16;
    return __builtin_bit_cast(float, u);
}

DEV bf16x8 ld_bf8(const unsigned short* p) {
    union { u16x8 u; bf16x8 b; } v;
    v.u = *(const u16x8*)p;
    return v.b;
}

DEV bf16x8 as_bf8(u16x8 u) {
    union { u16x8 u; bf16x8 b; } v;
    v.u = u;
    return v.b;
}

// ---------------- kernel 1: W fp32 -> bf16 transposed [n][k] ----------------
__global__ __launch_bounds__(256) void wconv_kernel(
        const float* __restrict__ Wq, const float* __restrict__ Wk,
        const float* __restrict__ Wv, unsigned short* __restrict__ wbt) {
    __shared__ unsigned short Tr[64 * 72];
    const int blk = blockIdx.x;
    const int head = blk >> 4, kt = blk & 15;
    const int k0 = kt * 64;
    const float* W = (head == 0) ? Wq : ((head == 1) ? Wk : Wv);
    const float sc = (head == 0) ? 0.045084220027780106f : 1.0f;  // log2(e)/32
    const int t = threadIdx.x;
    const int rrow = t >> 4, c4 = (t & 15) * 4;
    for (int i = 0; i < 4; ++i) {
        int krow = rrow + i * 16;
        f32x4 f = *(const f32x4*)(W + (size_t)(k0 + krow) * 64 + c4);
        Tr[(c4 + 0) * 72 + krow] = cvt_bf16(f[0] * sc);
        Tr[(c4 + 1) * 72 + krow] = cvt_bf16(f[1] * sc);
        Tr[(c4 + 2) * 72 + krow] = cvt_bf16(f[2] * sc);
        Tr[(c4 + 3) * 72 + krow] = cvt_bf16(f[3] * sc);
    }
    __syncthreads();
    const int n = t >> 2, off = (t & 3) * 16;
    u16x8 a0 = *(const u16x8*)&Tr[n * 72 + off];
    u16x8 a1 = *(const u16x8*)&Tr[n * 72 + off + 8];
    unsigned short* dst = wbt + head * 65536 + n * 1024 + k0 + off;
    *(u16x8*)dst = a0;
    *(u16x8*)(dst + 8) = a1;
}

// ---------------- kernel 2: projection q,k = x@W; v transposed -> vt --------
// 512 blocks x 4 waves; block = 32 rows x 192 cols; wave = 16 rows (wm=w&1)
// x 96 cols (wn=w>>1). NO LDS, NO barriers, NO LDS-DMA in the K-loop: x
// A-frags and W B-frags load direct global->register (precise per-register
// vmcnt from the compiler). x prefetched 2 steps ahead, W 1 step.
// Issue order = use order so a wait never drains younger prefetches.
// __launch_bounds__(256,2) pins the RP target so loads aren't sunk.
__global__ __launch_bounds__(256, 2) void proj_kernel(
        const float* __restrict__ x, const unsigned short* __restrict__ wbt,
        unsigned short* __restrict__ qws, unsigned short* __restrict__ kws,
        unsigned short* __restrict__ vtws) {
    __shared__ __align__(16) unsigned short TT2[64 * 48];  // v-transpose scratch

    const int t = threadIdx.x;
    const int lane = t & 63, w = t >> 6;
    const int quad = lane >> 4, c = lane & 15;
    const int wm = w & 1, wn = w >> 1;
    const int t0 = blockIdx.x * 32;

    // A-frag: row = t0+wm*16+c, k = ks + quad*8 + j  (two f32x4 per step)
    const float* xg = x + (size_t)(t0 + wm * 16 + c) * CE + quad * 8;
    // B-frag: col = wn*96 + nt*16 + c, k = ks + quad*8 + j (one u16x8)
    const unsigned short* wg = wbt + (size_t)(wn * 96 + c) * 1024 + quad * 8;

    f32x4 acc[6] = {};
    f32x4 x0a, x0b, x1a, x1b;
    u16x8 w0[6];

    // prologue: x for steps 0,1; W for step 0
    x0a = *(const f32x4*)(xg);
    x0b = *(const f32x4*)(xg + 4);
    x1a = *(const f32x4*)(xg + 32);
    x1b = *(const f32x4*)(xg + 36);
#pragma unroll
    for (int nt = 0; nt < 6; ++nt)
        w0[nt] = *(const u16x8*)(wg + nt * 16384);

    for (int step = 0; step < 32; ++step) {
        const int ksW = ((step + 1) & 31) * 32;   // wraps at end (discarded)
        const int ksX = ((step + 2) & 31) * 32;
        // ---- prefetch: W(step+1) first (used sooner), x(step+2) last ----
        u16x8 w1[6];
#pragma unroll
        for (int nt = 0; nt < 6; ++nt)
            w1[nt] = *(const u16x8*)(wg + nt * 16384 + ksW);
        f32x4 x2a = *(const f32x4*)(xg + ksX);
        f32x4 x2b = *(const f32x4*)(xg + ksX + 4);
        // ---- compute current step from registers ----
        u16x8 ap;
#pragma unroll
        for (int j = 0; j < 4; ++j) { ap[j] = cvt_bf16(x0a[j]); ap[4 + j] = cvt_bf16(x0b[j]); }
        bf16x8 af = as_bf8(ap);
#pragma unroll
        for (int nt = 0; nt < 6; ++nt)
            acc[nt] = MFMA(af, as_bf8(w0[nt]), acc[nt]);
        // ---- rotate ----
        x0a = x1a; x0b = x1b; x1a = x2a; x1b = x2b;
#pragma unroll
        for (int nt = 0; nt < 6; ++nt) w0[nt] = w1[nt];
    }

    // epilogue: q,k direct; v transposed via LDS (64 h x 32 t, stride 48)
    for (int nt = 0; nt < 6; ++nt) {
        int col = wn * 96 + nt * 16 + c;
        f32x4 a = acc[nt];
        for (int r4 = 0; r4 < 4; ++r4) {
            int row = wm * 16 + quad * 4 + r4;
            size_t tg = (size_t)(t0 + row);
            unsigned short hv = cvt_bf16(a[r4]);
            if (col < 64)       qws[tg * HS + col] = hv;
            else if (col < 128) kws[tg * HS + col - 64] = hv;
            else                TT2[(col - 128) * 48 + row] = hv;
        }
    }
    __syncthreads();
    {
        int h = t >> 2, off = (t & 3) * 8;
        u16x8 v = *(const u16x8*)&TT2[h * 48 + off];
        int b = t0 >> 11, tl0 = t0 & 2047;
        *(u16x8*)(vtws + (size_t)(b * 64 + h) * TT + tl0 + off) = v;
    }
}

// ---------------- kernel 3: flash, register frags, zero barriers ------------
// 512 blocks: sp=blk>>8; r8=blk&255; b=r8&7; qt=r8>>3 (sp1: 31-qt balance).
// Wave w owns q-rows qt*64+w*16+{0..15}; S^T = K.Q^T (lane c = q-row ->
// scalar softmax state). K/V/Q frags direct global->reg (r4/r5-verified
// layouts); K prefetched 1 iter ahead, issued AFTER current-iter pmask/V
// loads so their waits never drain it. P-transpose via wave-private LDS.
__global__ __launch_bounds__(256, 2) void flash_kernel(
        const unsigned short* __restrict__ qws, const unsigned short* __restrict__ kws,
        const unsigned short* __restrict__ vtws, const int* __restrict__ pmask,
        unsigned short* __restrict__ pO, float* __restrict__ pml) {
    __shared__ __align__(16) unsigned short Ps[4][1152];  // per-wave P [q16][kv 64+8]

    const int t = threadIdx.x, blk = blockIdx.x;
    const int sp = blk >> 8, r8i = blk & 255, b = r8i & 7;
    int qt = r8i >> 3;
    if (sp) qt = 31 - qt;
    if (sp && qt == 0) return;               // empty second split
    const int half = (qt + 2) >> 1;
    const int jbeg = sp ? half : 0;
    const int jend = sp ? qt + 1 : half;

    const int lane = t & 63, w = t >> 6;
    const int quad = lane >> 4, c = lane & 15;

    // A-frag bases: K row = kv, k = head dim; V^T row = h, k = kv
    const unsigned short* kbase = kws + (size_t)(b * TT + c) * HS + quad * 8;
    const unsigned short* vbase = vtws + (size_t)(b * 64 + c) * TT + quad * 8;
    const int* pmb = pmask + b * TT + quad * 4;

    // Q B-frag (n = qrow = c)
    bf16x8 qf[2];
#pragma unroll
    for (int kk = 0; kk < 2; ++kk)
        qf[kk] = ld_bf8(qws + (size_t)(b * TT + qt * 64 + w * 16 + c) * HS + kk * 32 + quad * 8);

    // prologue: K frags for iter jbeg
    u16x8 kc[4][2];
#pragma unroll
    for (int nt = 0; nt < 4; ++nt)
#pragma unroll
        for (int kk = 0; kk < 2; ++kk)
            kc[nt][kk] = *(const u16x8*)(kbase + (size_t)(jbeg * 64 + nt * 16) * HS + kk * 32);

    f32x4 o[4] = {};
    float m_run = -1e30f, l_run = 0.0f;

    for (int j = jbeg; j < jend; ++j) {
        const int kv0 = j * 64;
        // ---- 1) pmask current (earliest in-loop use) ----
        i32x4 pmv[4];
#pragma unroll
        for (int nt = 0; nt < 4; ++nt)
            pmv[nt] = *(const i32x4*)(pmb + kv0 + nt * 16);
        // ---- 2) V current (used at PV, ~500 cy of cover) ----
        u16x8 vc[4][2];
#pragma unroll
        for (int ht = 0; ht < 4; ++ht)
#pragma unroll
            for (int kx = 0; kx < 2; ++kx)
                vc[ht][kx] = *(const u16x8*)(vbase + (size_t)(ht * 16) * TT + kv0 + kx * 32);

        // ---- 3) S^T = K Q^T from prefetched kc ----
        f32x4 s4[4] = {};
#pragma unroll
        for (int kk = 0; kk < 2; ++kk)
#pragma unroll
            for (int nt = 0; nt < 4; ++nt)
                s4[nt] = MFMA(as_bf8(kc[nt][kk]), qf[kk], s4[nt]);

        // ---- 4) K prefetch for j+1 (newest; nothing in-iter waits on it) ----
        u16x8 kn[4][2];
        {
            int jn = (j + 1 < jend) ? j + 1 : j;   // last: dummy reload
#pragma unroll
            for (int nt = 0; nt < 4; ++nt)
#pragma unroll
                for (int kk = 0; kk < 2; ++kk)
                    kn[nt][kk] = *(const u16x8*)(kbase + (size_t)(jn * 64 + nt * 16) * HS + kk * 32);
        }

        // ---- 5) mask (causal on diagonal) + pad bias ----
        if (j == qt) {
            const int qrl = w * 16 + c;
#pragma unroll
            for (int nt = 0; nt < 4; ++nt)
#pragma unroll
                for (int r = 0; r < 4; ++r) {
                    int kvl = nt * 16 + quad * 4 + r;
                    bool dead = (kvl > qrl) || (pmv[nt][r] == 0);
                    s4[nt][r] = dead ? -1e30f : s4[nt][r];
                }
        } else {
#pragma unroll
            for (int nt = 0; nt < 4; ++nt)
#pragma unroll
                for (int r = 0; r < 4; ++r)
                    s4[nt][r] = (pmv[nt][r] == 0) ? -1e30f : s4[nt][r];
        }

        // ---- 6) online softmax: in-lane tree + 2 shfls, scalar state ----
        float mx = s4[0][0];
#pragma unroll
        for (int nt = 0; nt < 4; ++nt)
#pragma unroll
            for (int r = 0; r < 4; ++r) mx = fmaxf(mx, s4[nt][r]);
        mx = fmaxf(mx, __shfl_xor(mx, 16, 64));
        mx = fmaxf(mx, __shfl_xor(mx, 32, 64));
        float mnew = fmaxf(m_run, mx);
        float al = exp2f(m_run - mnew);
        m_run = mnew;
#pragma unroll
        for (int nt = 0; nt < 4; ++nt)
#pragma unroll
            for (int r = 0; r < 4; ++r) s4[nt][r] = exp2f(s4[nt][r] - mnew);
        float rs = 0.0f;
#pragma unroll
        for (int nt = 0; nt < 4; ++nt)
            rs += (s4[nt][0] + s4[nt][1]) + (s4[nt][2] + s4[nt][3]);
        rs += __shfl_xor(rs, 16, 64);
        rs += __shfl_xor(rs, 32, 64);
        l_run = l_run * al + rs;
#pragma unroll
        for (int ht = 0; ht < 4; ++ht)
#pragma unroll
            for (int r = 0; r < 4; ++r) o[ht][r] *= al;

        // ---- 7) P -> wave-private LDS, repack to B-frag (lgkm-precise) ----
#pragma unroll
        for (int nt = 0; nt < 4; ++nt) {
            u16x4 pk;
#pragma unroll
            for (int r = 0; r < 4; ++r) pk[r] = cvt_bf16(s4[nt][r]);
            *(u16x4*)&Ps[w][c * 72 + nt * 16 + quad * 4] = pk;
        }
        bf16x8 p0 = ld_bf8(&Ps[w][c * 72 + quad * 8]);
        bf16x8 p1 = ld_bf8(&Ps[w][c * 72 + 32 + quad * 8]);

        // ---- 8) O^T += V^T P^T ----
#pragma unroll
        for (int ht = 0; ht < 4; ++ht) {
            o[ht] = MFMA(as_bf8(vc[ht][0]), p0, o[ht]);
            o[ht] = MFMA(as_bf8(vc[ht][1]), p1, o[ht]);
        }

        // ---- rotate K prefetch ----
#pragma unroll
        for (int nt = 0; nt < 4; ++nt)
#pragma unroll
            for (int kk = 0; kk < 2; ++kk) kc[nt][kk] = kn[nt][kk];
    }

    // ---- store partials: slot = blk; pO [slot][row 64][h 64] ----
    unsigned short* po = pO + (size_t)blk * 4096;
#pragma unroll
    for (int ht = 0; ht < 4; ++ht) {
        u16x4 pk;
#pragma unroll
        for (int r = 0; r < 4; ++r) pk[r] = cvt_bf16(o[ht][r]);
        *(u16x4*)(po + (w * 16 + c) * 64 + ht * 16 + quad * 4) = pk;
    }
    if (quad == 0) {
        pml[(size_t)blk * 128 + (w * 16 + c) * 2] = m_run;
        pml[(size_t)blk * 128 + (w * 16 + c) * 2 + 1] = l_run;
    }
}

// ---------------- kernel 4: combine 2 splits -> final output ----------------
// 256 blocks (b,qt) x 256 thr; slot0 = qt*8+b, slot1 = 256 + (31-qt)*8 + b.
__global__ __launch_bounds__(256) void combine_kernel(
        const unsigned short* __restrict__ pO, const float* __restrict__ pml,
        float* __restrict__ out) {
    const int blk = blockIdx.x;
    const int qt = blk >> 3, b = blk & 7;
    const int s0 = qt * 8 + b, s1 = 256 + (31 - qt) * 8 + b;
    const bool two = (qt > 0);
    const int t = threadIdx.x, h = t & 63, rg = t >> 6;
    for (int i = 0; i < 16; ++i) {
        int row = rg + i * 4;
        float m0 = pml[(size_t)s0 * 128 + row * 2];
        float l0 = pml[(size_t)s0 * 128 + row * 2 + 1];
        float o0 = bf2f(pO[(size_t)s0 * 4096 + row * 64 + h]);
        float num, den;
        if (two) {
            float m1 = pml[(size_t)s1 * 128 + row * 2];
            float l1 = pml[(size_t)s1 * 128 + row * 2 + 1];
            float o1 = bf2f(pO[(size_t)s1 * 4096 + row * 64 + h]);
            float M = fmaxf(m0, m1);
            float w0 = exp2f(m0 - M), w1 = exp2f(m1 - M);
            num = o0 * w0 + o1 * w1;
            den = l0 * w0 + l1 * w1;
        } else {
            num = o0; den = l0;
        }
        out[(size_t)(b * TT + qt * 64 + row) * HS + h] = num / den;
    }
}

extern "C" void kernel_launch(void* const* d_in, const int* in_sizes, int n_in,
                              void* d_out, int out_size, void* d_ws, size_t ws_size,
                              hipStream_t stream) {
    const float* x  = (const float*)d_in[0];
    const int* pm   = (const int*)d_in[1];
    const float* Wq = (const float*)d_in[2];
    const float* Wk = (const float*)d_in[3];
    const float* Wv = (const float*)d_in[4];
    float* out = (float*)d_out;

    unsigned short* wsu  = (unsigned short*)d_ws;
    unsigned short* wbt  = wsu + WBT_E;
    unsigned short* qws  = wsu + Q_E;
    unsigned short* kws  = wsu + K_E;
    unsigned short* vtws = wsu + VT_E;
    unsigned short* pO   = wsu + PO_E;
    float* pml           = (float*)(wsu + PML_E);

    wconv_kernel<<<48, 256, 0, stream>>>(Wq, Wk, Wv, wbt);
    proj_kernel<<<512, 256, 0, stream>>>(x, wbt, qws, kws, vtws);
    flash_kernel<<<512, 256, 0, stream>>>(qws, kws, vtws, pm, pO, pml);
    combine_kernel<<<256, 256, 0, stream>>>(pO, pml, out);
}